// Round 6
// baseline (982.155 us; speedup 1.0000x reference)
//
#include <hip/hip_runtime.h>
#include <math.h>

typedef __attribute__((ext_vector_type(8))) short bf16x8;
typedef __attribute__((ext_vector_type(4))) float f32x4;

__device__ __forceinline__ unsigned short f2bf(float f) {
    unsigned int u = __float_as_uint(f);
    unsigned int r = (u + 0x7FFF + ((u >> 16) & 1)) >> 16;  // RNE
    return (unsigned short)r;
}
__device__ __forceinline__ float bf2f(unsigned short h) {
    return __uint_as_float((unsigned int)h << 16);
}
__device__ __forceinline__ void split_bf(float x, unsigned short& hi, unsigned short& lo) {
    hi = f2bf(x);
    lo = f2bf(x - bf2f(hi));
}

// ---------------- CSR build ----------------

__global__ void k_hist(const int* __restrict__ dst, int* __restrict__ deg, int e) {
    int t = blockIdx.x * 256 + threadIdx.x;
    if (t < e) atomicAdd(&deg[dst[t]], 1);
}

__global__ void k_scan1(const int* __restrict__ deg, int* __restrict__ tmp,
                        int* __restrict__ bsum, int n) {
    __shared__ int s[1024];
    int t = threadIdx.x;
    int g = blockIdx.x * 1024 + t;
    int v = (g < n) ? deg[g] : 0;
    s[t] = v;
    __syncthreads();
    for (int off = 1; off < 1024; off <<= 1) {
        int u = (t >= off) ? s[t - off] : 0;
        __syncthreads();
        s[t] += u;
        __syncthreads();
    }
    if (g < n) tmp[g] = s[t];
    if (t == 1023) bsum[blockIdx.x] = s[t];
}

__global__ void k_scan2(int* bsum, int nb) {
    int acc = 0;
    for (int b = 0; b < nb; ++b) { int v = bsum[b]; bsum[b] = acc; acc += v; }
}

__global__ void k_scan3(const int* __restrict__ deg, const int* __restrict__ tmp,
                        const int* __restrict__ bsum, int* __restrict__ rowptr,
                        int* __restrict__ cursor, int n) {
    int g = blockIdx.x * 256 + threadIdx.x;
    if (g < n) {
        int incl = tmp[g] + bsum[g >> 10];
        rowptr[g + 1] = incl;
        cursor[g] = incl - deg[g];
        if (g == 0) rowptr[0] = 0;
    }
}

__global__ void k_scatter(const int* __restrict__ src, const int* __restrict__ dst,
                          int* __restrict__ cursor, int* __restrict__ csr,
                          int* __restrict__ csr_dst, int e) {
    int t = blockIdx.x * 256 + threadIdx.x;
    if (t < e) {
        int d = dst[t];
        int pos = atomicAdd(&cursor[d], 1);
        csr[pos] = src[t];
        csr_dst[pos] = d;
    }
}

// ---------------- casts (split hi/lo) ----------------

__global__ void k_castx(const float* __restrict__ x, unsigned short* __restrict__ xhi,
                        unsigned short* __restrict__ xlo, int nelem) {
    int t = blockIdx.x * 256 + threadIdx.x;
    if (t < nelem) {
        unsigned short h, l;
        split_bf(x[t], h, l);
        xhi[t] = h; xlo[t] = l;
    }
}

__global__ void k_castw(const float* __restrict__ W, unsigned short* __restrict__ Whi,
                        unsigned short* __restrict__ Wlo, int K, int N) {
    int t = blockIdx.x * 256 + threadIdx.x;
    if (t < K * N) {
        int k = t / N, n = t - k * N;
        unsigned short h, l;
        split_bf(W[t], h, l);
        Whi[n * K + k] = h; Wlo[n * K + k] = l;
    }
}

// ------- split-bf16 MFMA GEMM (NT): C = A @ Bt^T, ~fp32 accuracy ----------

#define LDP 40

__global__ __launch_bounds__(256) void k_gemm_split(const unsigned short* __restrict__ Ahi,
                                                    const unsigned short* __restrict__ Alo,
                                                    const unsigned short* __restrict__ Bhi,
                                                    const unsigned short* __restrict__ Blo,
                                                    float* __restrict__ C,
                                                    int M, int Ncol, int K) {
    __shared__ unsigned short Ash[64 * LDP];
    __shared__ unsigned short Asl[64 * LDP];
    __shared__ unsigned short Bsh[64 * LDP];
    __shared__ unsigned short Bsl[64 * LDP];
    int t = threadIdx.x;
    int w = t >> 6, lane = t & 63;
    int lrow = lane & 15, kgrp = (lane >> 4) * 8;
    int row0 = blockIdx.x * 64, col0 = blockIdx.y * 64;
    int trow = t >> 2, tcol = (t & 3) * 8;

    f32x4 acc[4] = {{0.f, 0.f, 0.f, 0.f}, {0.f, 0.f, 0.f, 0.f},
                    {0.f, 0.f, 0.f, 0.f}, {0.f, 0.f, 0.f, 0.f}};

    for (int k0 = 0; k0 < K; k0 += 32) {
        uint4 ah = {0u,0u,0u,0u}, al = {0u,0u,0u,0u};
        uint4 bh = {0u,0u,0u,0u}, bl = {0u,0u,0u,0u};
        int gr = row0 + trow;
        if (gr < M) {
            ah = *(const uint4*)(Ahi + (size_t)gr * K + k0 + tcol);
            al = *(const uint4*)(Alo + (size_t)gr * K + k0 + tcol);
        }
        int gc = col0 + trow;
        if (gc < Ncol) {
            bh = *(const uint4*)(Bhi + (size_t)gc * K + k0 + tcol);
            bl = *(const uint4*)(Blo + (size_t)gc * K + k0 + tcol);
        }
        __syncthreads();
        *(uint4*)&Ash[trow * LDP + tcol] = ah;
        *(uint4*)&Asl[trow * LDP + tcol] = al;
        *(uint4*)&Bsh[trow * LDP + tcol] = bh;
        *(uint4*)&Bsl[trow * LDP + tcol] = bl;
        __syncthreads();
        bf16x8 vbh = *(const bf16x8*)&Bsh[(w * 16 + lrow) * LDP + kgrp];
        bf16x8 vbl = *(const bf16x8*)&Bsl[(w * 16 + lrow) * LDP + kgrp];
        #pragma unroll
        for (int mt = 0; mt < 4; ++mt) {
            bf16x8 vah = *(const bf16x8*)&Ash[(mt * 16 + lrow) * LDP + kgrp];
            bf16x8 val = *(const bf16x8*)&Asl[(mt * 16 + lrow) * LDP + kgrp];
            acc[mt] = __builtin_amdgcn_mfma_f32_16x16x32_bf16(vah, vbh, acc[mt], 0, 0, 0);
            acc[mt] = __builtin_amdgcn_mfma_f32_16x16x32_bf16(val, vbh, acc[mt], 0, 0, 0);
            acc[mt] = __builtin_amdgcn_mfma_f32_16x16x32_bf16(vah, vbl, acc[mt], 0, 0, 0);
        }
    }

    int ocol = col0 + w * 16 + lrow;
    if (ocol < Ncol) {
        int orow = (lane >> 4) * 4;
        #pragma unroll
        for (int mt = 0; mt < 4; ++mt) {
            #pragma unroll
            for (int r = 0; r < 4; ++r) {
                int m = row0 + mt * 16 + orow + r;
                if (m < M) C[(size_t)m * Ncol + ocol] = acc[mt][r];
            }
        }
    }
}

static inline void gemm_split(const unsigned short* Ah, const unsigned short* Al,
                              const unsigned short* Bh, const unsigned short* Bl,
                              float* C, int M, int Ncol, int K, hipStream_t st) {
    dim3 g((M + 63) / 64, (Ncol + 63) / 64);
    k_gemm_split<<<g, 256, 0, st>>>(Ah, Al, Bh, Bl, C, M, Ncol, K);
}

// ---------------- attention scores: el/er [N,H] ----------------

template <int H, int D>
__global__ __launch_bounds__(256) void k_attn(const float* __restrict__ feat,
                                              const float* __restrict__ al,
                                              const float* __restrict__ ar,
                                              float* __restrict__ el,
                                              float* __restrict__ er, int n) {
    int gw = blockIdx.x * 4 + (threadIdx.x >> 6);
    int lane = threadIdx.x & 63;
    int i = gw / H, h = gw % H;
    if (i >= n) return;
    float f = (lane < D) ? feat[i * (H * D) + h * D + lane] : 0.f;
    float wl = (lane < D) ? al[h * D + lane] : 0.f;
    float wr = (lane < D) ? ar[h * D + lane] : 0.f;
    float pl = f * wl, pr = f * wr;
    #pragma unroll
    for (int off = 32; off; off >>= 1) {
        pl += __shfl_xor(pl, off);
        pr += __shfl_xor(pr, off);
    }
    if (lane == 0) {
        el[i * H + h] = pl;
        er[i * H + h] = pr;
    }
}

// ---------------- edge softmax precompute ----------------

__device__ __forceinline__ float lrelu(float v) { return v > 0.f ? v : 0.2f * v; }

// per-(node,head) segment max
template <int H>
__global__ void k_emax(const int* __restrict__ rowptr, const int* __restrict__ csr,
                       const float* __restrict__ el, const float* __restrict__ er,
                       float* __restrict__ mbuf, int n) {
    int tid = blockIdx.x * 256 + threadIdx.x;
    if (tid >= n * H) return;
    int i = tid / H, h = tid - i * H;
    int s0 = rowptr[i], s1 = rowptr[i + 1];
    float eri = er[tid];
    float m = -INFINITY;
    for (int pos = s0; pos < s1; ++pos)
        m = fmaxf(m, lrelu(el[csr[pos] * H + h] + eri));
    mbuf[tid] = m;
}

// per-(edge,head) exp score (one exp per edge-head TOTAL)
template <int H>
__global__ void k_escore(const int* __restrict__ csr, const int* __restrict__ csr_dst,
                         const float* __restrict__ el, const float* __restrict__ er,
                         const float* __restrict__ mbuf, float* __restrict__ exbuf, int e) {
    int tid = blockIdx.x * 256 + threadIdx.x;
    if (tid >= e * H) return;
    int pos = tid / H, h = tid - pos * H;
    int s = csr[pos], d = csr_dst[pos];
    float v = lrelu(el[s * H + h] + er[d * H + h]);
    exbuf[tid] = __expf(v - mbuf[d * H + h]);
}

// ---------------- aggregation (single pass, no per-lane exp) ----------------

// H=4, D=64: one BLOCK per dst node; 256 thr = 4 heads x 64 ch.
template <int ACT, int SPLITOUT>
__global__ __launch_bounds__(256) void k_agg4(const int* __restrict__ rowptr,
                                              const int* __restrict__ csr,
                                              const float* __restrict__ exbuf,
                                              const float* __restrict__ feat,
                                              unsigned short* __restrict__ ohi,
                                              unsigned short* __restrict__ olo,
                                              float* __restrict__ ofp, int n) {
    int i = blockIdx.x;
    int t = threadIdx.x;
    int h = t >> 6;
    int s0 = rowptr[i], s1 = rowptr[i + 1];

    float den = 0.f, acc = 0.f;
    int pos = s0;
    for (; pos + 4 <= s1; pos += 4) {
        int sa = csr[pos], sb = csr[pos + 1], sc = csr[pos + 2], sd = csr[pos + 3];
        float xa = exbuf[pos * 4 + h];
        float xb = exbuf[(pos + 1) * 4 + h];
        float xc = exbuf[(pos + 2) * 4 + h];
        float xd = exbuf[(pos + 3) * 4 + h];
        float fa = feat[(size_t)sa * 256 + t];
        float fb = feat[(size_t)sb * 256 + t];
        float fc = feat[(size_t)sc * 256 + t];
        float fd = feat[(size_t)sd * 256 + t];
        den += (xa + xb) + (xc + xd);
        acc = fmaf(xa, fa, fmaf(xb, fb, fmaf(xc, fc, fmaf(xd, fd, acc))));
    }
    for (; pos < s1; ++pos) {
        int s = csr[pos];
        float ex = exbuf[pos * 4 + h];
        den += ex;
        acc = fmaf(ex, feat[(size_t)s * 256 + t], acc);
    }
    float o = (s1 > s0) ? acc / fmaxf(den, 1e-9f) : 0.f;
    if (ACT == 1) o = o > 0.f ? o : (__expf(o) - 1.f);
    if (SPLITOUT) {
        unsigned short hh, ll;
        split_bf(o, hh, ll);
        ohi[(size_t)i * 256 + t] = hh;
        olo[(size_t)i * 256 + t] = ll;
    } else {
        ofp[(size_t)i * 256 + t] = o;
    }
}

// H=1: one WAVE per dst node (4 waves/block).
template <int D, int ACT, int SPLITOUT>
__global__ __launch_bounds__(256) void k_agg1(const int* __restrict__ rowptr,
                                              const int* __restrict__ csr,
                                              const float* __restrict__ exbuf,
                                              const float* __restrict__ feat,
                                              unsigned short* __restrict__ ohi,
                                              unsigned short* __restrict__ olo,
                                              float* __restrict__ ofp, int n) {
    int i = blockIdx.x * 4 + (threadIdx.x >> 6);
    int lane = threadIdx.x & 63;
    if (i >= n) return;
    int s0 = rowptr[i], s1 = rowptr[i + 1];

    float den = 0.f, acc = 0.f;
    bool act = lane < D;
    int pos = s0;
    for (; pos + 4 <= s1; pos += 4) {
        int sa = csr[pos], sb = csr[pos + 1], sc = csr[pos + 2], sd = csr[pos + 3];
        float xa = exbuf[pos], xb = exbuf[pos + 1];
        float xc = exbuf[pos + 2], xd = exbuf[pos + 3];
        float fa = act ? feat[(size_t)sa * D + lane] : 0.f;
        float fb = act ? feat[(size_t)sb * D + lane] : 0.f;
        float fc = act ? feat[(size_t)sc * D + lane] : 0.f;
        float fd = act ? feat[(size_t)sd * D + lane] : 0.f;
        den += (xa + xb) + (xc + xd);
        acc = fmaf(xa, fa, fmaf(xb, fb, fmaf(xc, fc, fmaf(xd, fd, acc))));
    }
    for (; pos < s1; ++pos) {
        int s = csr[pos];
        float ex = exbuf[pos];
        den += ex;
        acc = fmaf(ex, act ? feat[(size_t)s * D + lane] : 0.f, acc);
    }
    float o = (s1 > s0) ? acc / fmaxf(den, 1e-9f) : 0.f;
    if (ACT == 1) o = o > 0.f ? o : (__expf(o) - 1.f);
    if (act) {
        if (SPLITOUT) {
            unsigned short hh, ll;
            split_bf(o, hh, ll);
            ohi[(size_t)i * D + lane] = hh;
            olo[(size_t)i * D + lane] = ll;
        } else {
            ofp[(size_t)i * D + lane] = o;
        }
    }
}

// ---------------- launch ----------------

extern "C" void kernel_launch(void* const* d_in, const int* in_sizes, int n_in,
                              void* d_out, int out_size, void* d_ws, size_t ws_size,
                              hipStream_t stream) {
    const float* x    = (const float*)d_in[0];
    const int*   src  = (const int*)d_in[1];
    const int*   dst  = (const int*)d_in[2];
    const float* W00  = (const float*)d_in[3];
    const float* a00l = (const float*)d_in[4];
    const float* a00r = (const float*)d_in[5];
    const float* W01  = (const float*)d_in[6];
    const float* a01l = (const float*)d_in[7];
    const float* a01r = (const float*)d_in[8];
    const float* W0f  = (const float*)d_in[9];
    const float* a0fl = (const float*)d_in[10];
    const float* a0fr = (const float*)d_in[11];
    const float* W10  = (const float*)d_in[12];
    const float* a10l = (const float*)d_in[13];
    const float* a10r = (const float*)d_in[14];
    const float* W1f  = (const float*)d_in[15];
    const float* a1fl = (const float*)d_in[16];
    const float* a1fr = (const float*)d_in[17];
    const float* W1o  = (const float*)d_in[18];
    const float* a1ol = (const float*)d_in[19];
    const float* a1or = (const float*)d_in[20];
    float* out = (float*)d_out;

    const int n = in_sizes[0] / 256;  // 50000
    const int e = in_sizes[1];        // 800000
    const int C = 40;

    char* p = (char*)d_ws;
    auto alloc = [&](size_t bytes) -> void* {
        void* r = (void*)p;
        p += (bytes + 255) & ~(size_t)255;
        return r;
    };
    int*   deg     = (int*)alloc((size_t)n * 4);
    int*   tmp     = (int*)alloc((size_t)n * 4);
    int*   bsum    = (int*)alloc(64 * 4);
    int*   rowptr  = (int*)alloc((size_t)(n + 1) * 4);
    int*   cursor  = (int*)alloc((size_t)n * 4);
    int*   csr     = (int*)alloc((size_t)e * 4);
    int*   csr_dst = (int*)alloc((size_t)e * 4);
    float* el      = (float*)alloc((size_t)n * 4 * 4);
    float* er      = (float*)alloc((size_t)n * 4 * 4);
    float* mbuf    = (float*)alloc((size_t)n * 4 * 4);
    float* exbuf   = (float*)alloc((size_t)e * 4 * 4);
    float* feat    = (float*)alloc((size_t)n * 256 * 4);
    unsigned short* xhi = (unsigned short*)alloc((size_t)n * 256 * 2);
    unsigned short* xlo = (unsigned short*)alloc((size_t)n * 256 * 2);
    unsigned short* hhi = (unsigned short*)alloc((size_t)n * 256 * 2);
    unsigned short* hlo = (unsigned short*)alloc((size_t)n * 256 * 2);
    unsigned short* W00h = (unsigned short*)alloc(256 * 256 * 2);
    unsigned short* W00l = (unsigned short*)alloc(256 * 256 * 2);
    unsigned short* W01h = (unsigned short*)alloc(256 * 64 * 2);
    unsigned short* W01l = (unsigned short*)alloc(256 * 64 * 2);
    unsigned short* W0fh = (unsigned short*)alloc(64 * 40 * 2);
    unsigned short* W0fl = (unsigned short*)alloc(64 * 40 * 2);
    unsigned short* W10h = (unsigned short*)alloc(256 * 256 * 2);
    unsigned short* W10l = (unsigned short*)alloc(256 * 256 * 2);
    unsigned short* W1fh = (unsigned short*)alloc(256 * 64 * 2);
    unsigned short* W1fl = (unsigned short*)alloc(256 * 64 * 2);
    unsigned short* W1oh = (unsigned short*)alloc(64 * 40 * 2);
    unsigned short* W1ol = (unsigned short*)alloc(64 * 40 * 2);

    // ---- CSR build ----
    hipMemsetAsync(deg, 0, (size_t)n * 4, stream);
    k_hist<<<(e + 255) / 256, 256, 0, stream>>>(dst, deg, e);
    int nb = (n + 1023) / 1024;
    k_scan1<<<nb, 1024, 0, stream>>>(deg, tmp, bsum, n);
    k_scan2<<<1, 1, 0, stream>>>(bsum, nb);
    k_scan3<<<(n + 255) / 256, 256, 0, stream>>>(deg, tmp, bsum, rowptr, cursor, n);
    k_scatter<<<(e + 255) / 256, 256, 0, stream>>>(src, dst, cursor, csr, csr_dst, e);

    // ---- casts ----
    int nel = n * 256;
    k_castx<<<(nel + 255) / 256, 256, 0, stream>>>(x, xhi, xlo, nel);
    k_castw<<<(256 * 256 + 255) / 256, 256, 0, stream>>>(W00, W00h, W00l, 256, 256);
    k_castw<<<(256 * 64 + 255) / 256, 256, 0, stream>>>(W01, W01h, W01l, 256, 64);
    k_castw<<<(64 * 40 + 255) / 256, 256, 0, stream>>>(W0f, W0fh, W0fl, 64, 40);
    k_castw<<<(256 * 256 + 255) / 256, 256, 0, stream>>>(W10, W10h, W10l, 256, 256);
    k_castw<<<(256 * 64 + 255) / 256, 256, 0, stream>>>(W1f, W1fh, W1fl, 256, 64);
    k_castw<<<(64 * 40 + 255) / 256, 256, 0, stream>>>(W1o, W1oh, W1ol, 64, 40);

    int gw4 = (n * 4 + 3) / 4;
    int gw1 = (n + 3) / 4;
    int gm4 = (n * 4 + 255) / 256, gm1 = (n + 255) / 256;
    int ge4 = (e * 4 + 255) / 256, ge1 = (e + 255) / 256;

    // ---- branch 0 ----
    gemm_split(xhi, xlo, W00h, W00l, feat, n, 256, 256, stream);
    k_attn<4, 64><<<gw4, 256, 0, stream>>>(feat, a00l, a00r, el, er, n);
    k_emax<4><<<gm4, 256, 0, stream>>>(rowptr, csr, el, er, mbuf, n);
    k_escore<4><<<ge4, 256, 0, stream>>>(csr, csr_dst, el, er, mbuf, exbuf, e);
    k_agg4<1, 1><<<n, 256, 0, stream>>>(rowptr, csr, exbuf, feat, hhi, hlo, nullptr, n);

    gemm_split(hhi, hlo, W01h, W01l, feat, n, 64, 256, stream);
    k_attn<1, 64><<<gw1, 256, 0, stream>>>(feat, a01l, a01r, el, er, n);
    k_emax<1><<<gm1, 256, 0, stream>>>(rowptr, csr, el, er, mbuf, n);
    k_escore<1><<<ge1, 256, 0, stream>>>(csr, csr_dst, el, er, mbuf, exbuf, e);
    k_agg1<64, 1, 1><<<gw1, 256, 0, stream>>>(rowptr, csr, exbuf, feat, hhi, hlo, nullptr, n);

    gemm_split(hhi, hlo, W0fh, W0fl, feat, n, C, 64, stream);
    k_attn<1, 40><<<gw1, 256, 0, stream>>>(feat, a0fl, a0fr, el, er, n);
    k_emax<1><<<gm1, 256, 0, stream>>>(rowptr, csr, el, er, mbuf, n);
    k_escore<1><<<ge1, 256, 0, stream>>>(csr, csr_dst, el, er, mbuf, exbuf, e);
    k_agg1<40, 0, 0><<<gw1, 256, 0, stream>>>(rowptr, csr, exbuf, feat, nullptr, nullptr, out, n);

    // ---- branch 1 ----
    gemm_split(xhi, xlo, W10h, W10l, feat, n, 256, 256, stream);
    k_attn<4, 64><<<gw4, 256, 0, stream>>>(feat, a10l, a10r, el, er, n);
    k_emax<4><<<gm4, 256, 0, stream>>>(rowptr, csr, el, er, mbuf, n);
    k_escore<4><<<ge4, 256, 0, stream>>>(csr, csr_dst, el, er, mbuf, exbuf, e);
    k_agg4<1, 1><<<n, 256, 0, stream>>>(rowptr, csr, exbuf, feat, hhi, hlo, nullptr, n);

    gemm_split(hhi, hlo, W1fh, W1fl, feat, n, 64, 256, stream);
    k_attn<1, 64><<<gw1, 256, 0, stream>>>(feat, a1fl, a1fr, el, er, n);
    k_emax<1><<<gm1, 256, 0, stream>>>(rowptr, csr, el, er, mbuf, n);
    k_escore<1><<<ge1, 256, 0, stream>>>(csr, csr_dst, el, er, mbuf, exbuf, e);
    k_agg1<64, 0, 1><<<gw1, 256, 0, stream>>>(rowptr, csr, exbuf, feat, hhi, hlo, nullptr, n);

    gemm_split(hhi, hlo, W1oh, W1ol, feat, n, C, 64, stream);
    k_attn<1, 40><<<gw1, 256, 0, stream>>>(feat, a1ol, a1or, el, er, n);
    k_emax<1><<<gm1, 256, 0, stream>>>(rowptr, csr, el, er, mbuf, n);
    k_escore<1><<<ge1, 256, 0, stream>>>(csr, csr_dst, el, er, mbuf, exbuf, e);
    k_agg1<40, 1, 0><<<gw1, 256, 0, stream>>>(rowptr, csr, exbuf, feat, nullptr, nullptr,
                                              out + (size_t)n * C, n);
}

// Round 7
// 902.439 us; speedup vs baseline: 1.0883x; 1.0883x over previous
//
#include <hip/hip_runtime.h>
#include <math.h>

typedef __attribute__((ext_vector_type(8))) short bf16x8;
typedef __attribute__((ext_vector_type(4))) float f32x4;

__device__ __forceinline__ unsigned short f2bf(float f) {
    unsigned int u = __float_as_uint(f);
    unsigned int r = (u + 0x7FFF + ((u >> 16) & 1)) >> 16;  // RNE
    return (unsigned short)r;
}
__device__ __forceinline__ float bf2f(unsigned short h) {
    return __uint_as_float((unsigned int)h << 16);
}
__device__ __forceinline__ void split_bf(float x, unsigned short& hi, unsigned short& lo) {
    hi = f2bf(x);
    lo = f2bf(x - bf2f(hi));
}

// ---------------- CSR build ----------------

__global__ void k_hist(const int* __restrict__ dst, int* __restrict__ deg, int e) {
    int t = blockIdx.x * 256 + threadIdx.x;
    if (t < e) atomicAdd(&deg[dst[t]], 1);
}

__global__ void k_scan1(const int* __restrict__ deg, int* __restrict__ tmp,
                        int* __restrict__ bsum, int n) {
    __shared__ int s[1024];
    int t = threadIdx.x;
    int g = blockIdx.x * 1024 + t;
    int v = (g < n) ? deg[g] : 0;
    s[t] = v;
    __syncthreads();
    for (int off = 1; off < 1024; off <<= 1) {
        int u = (t >= off) ? s[t - off] : 0;
        __syncthreads();
        s[t] += u;
        __syncthreads();
    }
    if (g < n) tmp[g] = s[t];
    if (t == 1023) bsum[blockIdx.x] = s[t];
}

__global__ void k_scan2(int* bsum, int nb) {
    int acc = 0;
    for (int b = 0; b < nb; ++b) { int v = bsum[b]; bsum[b] = acc; acc += v; }
}

__global__ void k_scan3(const int* __restrict__ deg, const int* __restrict__ tmp,
                        const int* __restrict__ bsum, int* __restrict__ rowptr,
                        int* __restrict__ cursor, int n) {
    int g = blockIdx.x * 256 + threadIdx.x;
    if (g < n) {
        int incl = tmp[g] + bsum[g >> 10];
        rowptr[g + 1] = incl;
        cursor[g] = incl - deg[g];
        if (g == 0) rowptr[0] = 0;
    }
}

__global__ void k_scatter(const int* __restrict__ src, const int* __restrict__ dst,
                          int* __restrict__ cursor, int* __restrict__ csr, int e) {
    int t = blockIdx.x * 256 + threadIdx.x;
    if (t < e) {
        int d = dst[t];
        int pos = atomicAdd(&cursor[d], 1);
        csr[pos] = src[t];
    }
}

// ---------------- casts (split hi/lo) ----------------

__global__ void k_castx(const float* __restrict__ x, unsigned short* __restrict__ xhi,
                        unsigned short* __restrict__ xlo, int nelem) {
    int t = blockIdx.x * 256 + threadIdx.x;
    if (t < nelem) {
        unsigned short h, l;
        split_bf(x[t], h, l);
        xhi[t] = h; xlo[t] = l;
    }
}

__global__ void k_castw(const float* __restrict__ W, unsigned short* __restrict__ Whi,
                        unsigned short* __restrict__ Wlo, int K, int N) {
    int t = blockIdx.x * 256 + threadIdx.x;
    if (t < K * N) {
        int k = t / N, n = t - k * N;
        unsigned short h, l;
        split_bf(W[t], h, l);
        Whi[n * K + k] = h; Wlo[n * K + k] = l;
    }
}

// ------- split-bf16 MFMA GEMM (NT): C = A @ Bt^T, ~fp32 accuracy ----------
// Output written as fp16 (feeds gathers in agg; 11-bit mantissa is enough).

#define LDP 40

__global__ __launch_bounds__(256) void k_gemm_split(const unsigned short* __restrict__ Ahi,
                                                    const unsigned short* __restrict__ Alo,
                                                    const unsigned short* __restrict__ Bhi,
                                                    const unsigned short* __restrict__ Blo,
                                                    _Float16* __restrict__ C,
                                                    int M, int Ncol, int K) {
    __shared__ unsigned short Ash[64 * LDP];
    __shared__ unsigned short Asl[64 * LDP];
    __shared__ unsigned short Bsh[64 * LDP];
    __shared__ unsigned short Bsl[64 * LDP];
    int t = threadIdx.x;
    int w = t >> 6, lane = t & 63;
    int lrow = lane & 15, kgrp = (lane >> 4) * 8;
    int row0 = blockIdx.x * 64, col0 = blockIdx.y * 64;
    int trow = t >> 2, tcol = (t & 3) * 8;

    f32x4 acc[4] = {{0.f, 0.f, 0.f, 0.f}, {0.f, 0.f, 0.f, 0.f},
                    {0.f, 0.f, 0.f, 0.f}, {0.f, 0.f, 0.f, 0.f}};

    for (int k0 = 0; k0 < K; k0 += 32) {
        uint4 ah = {0u,0u,0u,0u}, al = {0u,0u,0u,0u};
        uint4 bh = {0u,0u,0u,0u}, bl = {0u,0u,0u,0u};
        int gr = row0 + trow;
        if (gr < M) {
            ah = *(const uint4*)(Ahi + (size_t)gr * K + k0 + tcol);
            al = *(const uint4*)(Alo + (size_t)gr * K + k0 + tcol);
        }
        int gc = col0 + trow;
        if (gc < Ncol) {
            bh = *(const uint4*)(Bhi + (size_t)gc * K + k0 + tcol);
            bl = *(const uint4*)(Blo + (size_t)gc * K + k0 + tcol);
        }
        __syncthreads();
        *(uint4*)&Ash[trow * LDP + tcol] = ah;
        *(uint4*)&Asl[trow * LDP + tcol] = al;
        *(uint4*)&Bsh[trow * LDP + tcol] = bh;
        *(uint4*)&Bsl[trow * LDP + tcol] = bl;
        __syncthreads();
        bf16x8 vbh = *(const bf16x8*)&Bsh[(w * 16 + lrow) * LDP + kgrp];
        bf16x8 vbl = *(const bf16x8*)&Bsl[(w * 16 + lrow) * LDP + kgrp];
        #pragma unroll
        for (int mt = 0; mt < 4; ++mt) {
            bf16x8 vah = *(const bf16x8*)&Ash[(mt * 16 + lrow) * LDP + kgrp];
            bf16x8 val = *(const bf16x8*)&Asl[(mt * 16 + lrow) * LDP + kgrp];
            acc[mt] = __builtin_amdgcn_mfma_f32_16x16x32_bf16(vah, vbh, acc[mt], 0, 0, 0);
            acc[mt] = __builtin_amdgcn_mfma_f32_16x16x32_bf16(val, vbh, acc[mt], 0, 0, 0);
            acc[mt] = __builtin_amdgcn_mfma_f32_16x16x32_bf16(vah, vbl, acc[mt], 0, 0, 0);
        }
    }

    int ocol = col0 + w * 16 + lrow;
    if (ocol < Ncol) {
        int orow = (lane >> 4) * 4;
        #pragma unroll
        for (int mt = 0; mt < 4; ++mt) {
            #pragma unroll
            for (int r = 0; r < 4; ++r) {
                int m = row0 + mt * 16 + orow + r;
                if (m < M) C[(size_t)m * Ncol + ocol] = (_Float16)acc[mt][r];
            }
        }
    }
}

static inline void gemm_split(const unsigned short* Ah, const unsigned short* Al,
                              const unsigned short* Bh, const unsigned short* Bl,
                              _Float16* C, int M, int Ncol, int K, hipStream_t st) {
    dim3 g((M + 63) / 64, (Ncol + 63) / 64);
    k_gemm_split<<<g, 256, 0, st>>>(Ah, Al, Bh, Bl, C, M, Ncol, K);
}

// ---------------- attention scores: el/er [N,H] ----------------

template <int H, int D>
__global__ __launch_bounds__(256) void k_attn(const _Float16* __restrict__ feat,
                                              const float* __restrict__ al,
                                              const float* __restrict__ ar,
                                              float* __restrict__ el,
                                              float* __restrict__ er, int n) {
    int gw = blockIdx.x * 4 + (threadIdx.x >> 6);
    int lane = threadIdx.x & 63;
    int i = gw / H, h = gw % H;
    if (i >= n) return;
    float f = (lane < D) ? (float)feat[i * (H * D) + h * D + lane] : 0.f;
    float wl = (lane < D) ? al[h * D + lane] : 0.f;
    float wr = (lane < D) ? ar[h * D + lane] : 0.f;
    float pl = f * wl, pr = f * wr;
    #pragma unroll
    for (int off = 32; off; off >>= 1) {
        pl += __shfl_xor(pl, off);
        pr += __shfl_xor(pr, off);
    }
    if (lane == 0) {
        el[i * H + h] = pl;
        er[i * H + h] = pr;
    }
}

// ---------------- edge-softmax aggregation (fused, cooperative exp) --------
// Pass 1: lane=edge segment max (wave reduce).
// Pass 2: chunks of 64 edges: lane computes its edge's exp ONCE, then the
// (ex, src) pair is shfl-broadcast to all channel lanes for the FMA loop.
// No extra kernels, no exbuf traffic, 1/64th of R5's scalar work.

__device__ __forceinline__ float lrelu(float v) { return v > 0.f ? v : 0.2f * v; }

// H=4, D=64: one BLOCK per dst node; 256 thr = 4 heads x 64 ch.
template <int ACT, int SPLITOUT>
__global__ __launch_bounds__(256) void k_agg4(const int* __restrict__ rowptr,
                                              const int* __restrict__ csr,
                                              const float* __restrict__ el,
                                              const float* __restrict__ er,
                                              const _Float16* __restrict__ feat,
                                              unsigned short* __restrict__ ohi,
                                              unsigned short* __restrict__ olo,
                                              float* __restrict__ ofp, int n) {
    int i = blockIdx.x;
    int t = threadIdx.x;
    int h = t >> 6;
    int lane = t & 63;
    int s0 = rowptr[i], s1 = rowptr[i + 1];
    float eri = er[i * 4 + h];

    float m = -INFINITY;
    for (int e = s0 + lane; e < s1; e += 64)
        m = fmaxf(m, lrelu(el[csr[e] * 4 + h] + eri));
    #pragma unroll
    for (int off = 32; off; off >>= 1) m = fmaxf(m, __shfl_xor(m, off));

    float den = 0.f, acc = 0.f;
    for (int c = s0; c < s1; c += 64) {
        int e = c + lane;
        int s = 0;
        float ex = 0.f;
        if (e < s1) {
            s = csr[e];
            ex = __expf(lrelu(el[s * 4 + h] + eri) - m);
        }
        den += ex;
        int cnt = min(64, s1 - c);
        int j = 0;
        for (; j + 4 <= cnt; j += 4) {
            int sj0 = __shfl(s, j), sj1 = __shfl(s, j + 1);
            int sj2 = __shfl(s, j + 2), sj3 = __shfl(s, j + 3);
            float x0 = __shfl(ex, j), x1 = __shfl(ex, j + 1);
            float x2 = __shfl(ex, j + 2), x3 = __shfl(ex, j + 3);
            float f0 = (float)feat[(size_t)sj0 * 256 + t];
            float f1 = (float)feat[(size_t)sj1 * 256 + t];
            float f2 = (float)feat[(size_t)sj2 * 256 + t];
            float f3 = (float)feat[(size_t)sj3 * 256 + t];
            acc = fmaf(x0, f0, fmaf(x1, f1, fmaf(x2, f2, fmaf(x3, f3, acc))));
        }
        for (; j < cnt; ++j) {
            int sj = __shfl(s, j);
            float xj = __shfl(ex, j);
            acc = fmaf(xj, (float)feat[(size_t)sj * 256 + t], acc);
        }
    }
    #pragma unroll
    for (int off = 32; off; off >>= 1) den += __shfl_xor(den, off);

    float o = (s1 > s0) ? acc / fmaxf(den, 1e-9f) : 0.f;
    if (ACT == 1) o = o > 0.f ? o : (__expf(o) - 1.f);
    if (SPLITOUT) {
        unsigned short hh, ll;
        split_bf(o, hh, ll);
        ohi[(size_t)i * 256 + t] = hh;
        olo[(size_t)i * 256 + t] = ll;
    } else {
        ofp[(size_t)i * 256 + t] = o;
    }
}

// H=1: one WAVE per dst node (4 waves/block), same cooperative structure.
template <int D, int ACT, int SPLITOUT>
__global__ __launch_bounds__(256) void k_agg1(const int* __restrict__ rowptr,
                                              const int* __restrict__ csr,
                                              const float* __restrict__ el,
                                              const float* __restrict__ er,
                                              const _Float16* __restrict__ feat,
                                              unsigned short* __restrict__ ohi,
                                              unsigned short* __restrict__ olo,
                                              float* __restrict__ ofp, int n) {
    int i = blockIdx.x * 4 + (threadIdx.x >> 6);
    int lane = threadIdx.x & 63;
    if (i >= n) return;
    int s0 = rowptr[i], s1 = rowptr[i + 1];
    float eri = er[i];
    bool act = lane < D;

    float m = -INFINITY;
    for (int e = s0 + lane; e < s1; e += 64)
        m = fmaxf(m, lrelu(el[csr[e]] + eri));
    #pragma unroll
    for (int off = 32; off; off >>= 1) m = fmaxf(m, __shfl_xor(m, off));

    float den = 0.f, acc = 0.f;
    for (int c = s0; c < s1; c += 64) {
        int e = c + lane;
        int s = 0;
        float ex = 0.f;
        if (e < s1) {
            s = csr[e];
            ex = __expf(lrelu(el[s] + eri) - m);
        }
        den += ex;
        int cnt = min(64, s1 - c);
        int j = 0;
        for (; j + 4 <= cnt; j += 4) {
            int sj0 = __shfl(s, j), sj1 = __shfl(s, j + 1);
            int sj2 = __shfl(s, j + 2), sj3 = __shfl(s, j + 3);
            float x0 = __shfl(ex, j), x1 = __shfl(ex, j + 1);
            float x2 = __shfl(ex, j + 2), x3 = __shfl(ex, j + 3);
            float f0 = act ? (float)feat[(size_t)sj0 * D + lane] : 0.f;
            float f1 = act ? (float)feat[(size_t)sj1 * D + lane] : 0.f;
            float f2 = act ? (float)feat[(size_t)sj2 * D + lane] : 0.f;
            float f3 = act ? (float)feat[(size_t)sj3 * D + lane] : 0.f;
            acc = fmaf(x0, f0, fmaf(x1, f1, fmaf(x2, f2, fmaf(x3, f3, acc))));
        }
        for (; j < cnt; ++j) {
            int sj = __shfl(s, j);
            float xj = __shfl(ex, j);
            acc = fmaf(xj, act ? (float)feat[(size_t)sj * D + lane] : 0.f, acc);
        }
    }
    #pragma unroll
    for (int off = 32; off; off >>= 1) den += __shfl_xor(den, off);

    float o = (s1 > s0) ? acc / fmaxf(den, 1e-9f) : 0.f;
    if (ACT == 1) o = o > 0.f ? o : (__expf(o) - 1.f);
    if (act) {
        if (SPLITOUT) {
            unsigned short hh, ll;
            split_bf(o, hh, ll);
            ohi[(size_t)i * D + lane] = hh;
            olo[(size_t)i * D + lane] = ll;
        } else {
            ofp[(size_t)i * D + lane] = o;
        }
    }
}

// ---------------- launch ----------------

extern "C" void kernel_launch(void* const* d_in, const int* in_sizes, int n_in,
                              void* d_out, int out_size, void* d_ws, size_t ws_size,
                              hipStream_t stream) {
    const float* x    = (const float*)d_in[0];
    const int*   src  = (const int*)d_in[1];
    const int*   dst  = (const int*)d_in[2];
    const float* W00  = (const float*)d_in[3];
    const float* a00l = (const float*)d_in[4];
    const float* a00r = (const float*)d_in[5];
    const float* W01  = (const float*)d_in[6];
    const float* a01l = (const float*)d_in[7];
    const float* a01r = (const float*)d_in[8];
    const float* W0f  = (const float*)d_in[9];
    const float* a0fl = (const float*)d_in[10];
    const float* a0fr = (const float*)d_in[11];
    const float* W10  = (const float*)d_in[12];
    const float* a10l = (const float*)d_in[13];
    const float* a10r = (const float*)d_in[14];
    const float* W1f  = (const float*)d_in[15];
    const float* a1fl = (const float*)d_in[16];
    const float* a1fr = (const float*)d_in[17];
    const float* W1o  = (const float*)d_in[18];
    const float* a1ol = (const float*)d_in[19];
    const float* a1or = (const float*)d_in[20];
    float* out = (float*)d_out;

    const int n = in_sizes[0] / 256;  // 50000
    const int e = in_sizes[1];        // 800000
    const int C = 40;

    char* p = (char*)d_ws;
    auto alloc = [&](size_t bytes) -> void* {
        void* r = (void*)p;
        p += (bytes + 255) & ~(size_t)255;
        return r;
    };
    int*   deg     = (int*)alloc((size_t)n * 4);
    int*   tmp     = (int*)alloc((size_t)n * 4);
    int*   bsum    = (int*)alloc(64 * 4);
    int*   rowptr  = (int*)alloc((size_t)(n + 1) * 4);
    int*   cursor  = (int*)alloc((size_t)n * 4);
    int*   csr     = (int*)alloc((size_t)e * 4);
    float* el      = (float*)alloc((size_t)n * 4 * 4);
    float* er      = (float*)alloc((size_t)n * 4 * 4);
    _Float16* feat = (_Float16*)alloc((size_t)n * 256 * 2 + 256);
    unsigned short* xhi = (unsigned short*)alloc((size_t)n * 256 * 2);
    unsigned short* xlo = (unsigned short*)alloc((size_t)n * 256 * 2);
    unsigned short* hhi = (unsigned short*)alloc((size_t)n * 256 * 2);
    unsigned short* hlo = (unsigned short*)alloc((size_t)n * 256 * 2);
    unsigned short* W00h = (unsigned short*)alloc(256 * 256 * 2);
    unsigned short* W00l = (unsigned short*)alloc(256 * 256 * 2);
    unsigned short* W01h = (unsigned short*)alloc(256 * 64 * 2);
    unsigned short* W01l = (unsigned short*)alloc(256 * 64 * 2);
    unsigned short* W0fh = (unsigned short*)alloc(64 * 40 * 2);
    unsigned short* W0fl = (unsigned short*)alloc(64 * 40 * 2);
    unsigned short* W10h = (unsigned short*)alloc(256 * 256 * 2);
    unsigned short* W10l = (unsigned short*)alloc(256 * 256 * 2);
    unsigned short* W1fh = (unsigned short*)alloc(256 * 64 * 2);
    unsigned short* W1fl = (unsigned short*)alloc(256 * 64 * 2);
    unsigned short* W1oh = (unsigned short*)alloc(64 * 40 * 2);
    unsigned short* W1ol = (unsigned short*)alloc(64 * 40 * 2);

    // ---- CSR build ----
    hipMemsetAsync(deg, 0, (size_t)n * 4, stream);
    k_hist<<<(e + 255) / 256, 256, 0, stream>>>(dst, deg, e);
    int nb = (n + 1023) / 1024;
    k_scan1<<<nb, 1024, 0, stream>>>(deg, tmp, bsum, n);
    k_scan2<<<1, 1, 0, stream>>>(bsum, nb);
    k_scan3<<<(n + 255) / 256, 256, 0, stream>>>(deg, tmp, bsum, rowptr, cursor, n);
    k_scatter<<<(e + 255) / 256, 256, 0, stream>>>(src, dst, cursor, csr, e);

    // ---- casts ----
    int nel = n * 256;
    k_castx<<<(nel + 255) / 256, 256, 0, stream>>>(x, xhi, xlo, nel);
    k_castw<<<(256 * 256 + 255) / 256, 256, 0, stream>>>(W00, W00h, W00l, 256, 256);
    k_castw<<<(256 * 64 + 255) / 256, 256, 0, stream>>>(W01, W01h, W01l, 256, 64);
    k_castw<<<(64 * 40 + 255) / 256, 256, 0, stream>>>(W0f, W0fh, W0fl, 64, 40);
    k_castw<<<(256 * 256 + 255) / 256, 256, 0, stream>>>(W10, W10h, W10l, 256, 256);
    k_castw<<<(256 * 64 + 255) / 256, 256, 0, stream>>>(W1f, W1fh, W1fl, 256, 64);
    k_castw<<<(64 * 40 + 255) / 256, 256, 0, stream>>>(W1o, W1oh, W1ol, 64, 40);

    int gw4 = (n * 4 + 3) / 4;
    int gw1 = (n + 3) / 4;

    // ---- branch 0 ----
    gemm_split(xhi, xlo, W00h, W00l, feat, n, 256, 256, stream);
    k_attn<4, 64><<<gw4, 256, 0, stream>>>(feat, a00l, a00r, el, er, n);
    k_agg4<1, 1><<<n, 256, 0, stream>>>(rowptr, csr, el, er, feat, hhi, hlo, nullptr, n);

    gemm_split(hhi, hlo, W01h, W01l, feat, n, 64, 256, stream);
    k_attn<1, 64><<<gw1, 256, 0, stream>>>(feat, a01l, a01r, el, er, n);
    k_agg1<64, 1, 1><<<gw1, 256, 0, stream>>>(rowptr, csr, el, er, feat, hhi, hlo, nullptr, n);

    gemm_split(hhi, hlo, W0fh, W0fl, feat, n, C, 64, stream);
    k_attn<1, 40><<<gw1, 256, 0, stream>>>(feat, a0fl, a0fr, el, er, n);
    k_agg1<40, 0, 0><<<gw1, 256, 0, stream>>>(rowptr, csr, el, er, feat, nullptr, nullptr, out, n);

    // ---- branch 1 ----
    gemm_split(xhi, xlo, W10h, W10l, feat, n, 256, 256, stream);
    k_attn<4, 64><<<gw4, 256, 0, stream>>>(feat, a10l, a10r, el, er, n);
    k_agg4<1, 1><<<n, 256, 0, stream>>>(rowptr, csr, el, er, feat, hhi, hlo, nullptr, n);

    gemm_split(hhi, hlo, W1fh, W1fl, feat, n, 64, 256, stream);
    k_attn<1, 64><<<gw1, 256, 0, stream>>>(feat, a1fl, a1fr, el, er, n);
    k_agg1<64, 0, 1><<<gw1, 256, 0, stream>>>(rowptr, csr, el, er, feat, hhi, hlo, nullptr, n);

    gemm_split(hhi, hlo, W1oh, W1ol, feat, n, C, 64, stream);
    k_attn<1, 40><<<gw1, 256, 0, stream>>>(feat, a1ol, a1or, el, er, n);
    k_agg1<40, 1, 0><<<gw1, 256, 0, stream>>>(rowptr, csr, el, er, feat, nullptr, nullptr,
                                              out + (size_t)n * C, n);
}

// Round 8
// 837.206 us; speedup vs baseline: 1.1731x; 1.0779x over previous
//
#include <hip/hip_runtime.h>
#include <math.h>

typedef __attribute__((ext_vector_type(8))) short bf16x8;
typedef __attribute__((ext_vector_type(4))) float f32x4;

__device__ __forceinline__ unsigned short f2bf(float f) {
    unsigned int u = __float_as_uint(f);
    unsigned int r = (u + 0x7FFF + ((u >> 16) & 1)) >> 16;  // RNE
    return (unsigned short)r;
}
__device__ __forceinline__ float bf2f(unsigned short h) {
    return __uint_as_float((unsigned int)h << 16);
}
__device__ __forceinline__ void split_bf(float x, unsigned short& hi, unsigned short& lo) {
    hi = f2bf(x);
    lo = f2bf(x - bf2f(hi));
}

// ---------------- CSR build ----------------

__global__ void k_hist(const int* __restrict__ dst, int* __restrict__ deg, int e) {
    int t = blockIdx.x * 256 + threadIdx.x;
    if (t < e) atomicAdd(&deg[dst[t]], 1);
}

__global__ void k_scan1(const int* __restrict__ deg, int* __restrict__ tmp,
                        int* __restrict__ bsum, int n) {
    __shared__ int s[1024];
    int t = threadIdx.x;
    int g = blockIdx.x * 1024 + t;
    int v = (g < n) ? deg[g] : 0;
    s[t] = v;
    __syncthreads();
    for (int off = 1; off < 1024; off <<= 1) {
        int u = (t >= off) ? s[t - off] : 0;
        __syncthreads();
        s[t] += u;
        __syncthreads();
    }
    if (g < n) tmp[g] = s[t];
    if (t == 1023) bsum[blockIdx.x] = s[t];
}

__global__ void k_scan2(int* bsum, int nb) {
    int acc = 0;
    for (int b = 0; b < nb; ++b) { int v = bsum[b]; bsum[b] = acc; acc += v; }
}

__global__ void k_scan3(const int* __restrict__ deg, const int* __restrict__ tmp,
                        const int* __restrict__ bsum, int* __restrict__ rowptr,
                        int* __restrict__ cursor, int n) {
    int g = blockIdx.x * 256 + threadIdx.x;
    if (g < n) {
        int incl = tmp[g] + bsum[g >> 10];
        rowptr[g + 1] = incl;
        cursor[g] = incl - deg[g];
        if (g == 0) rowptr[0] = 0;
    }
}

__global__ void k_scatter(const int* __restrict__ src, const int* __restrict__ dst,
                          int* __restrict__ cursor, int* __restrict__ csr, int e) {
    int t = blockIdx.x * 256 + threadIdx.x;
    if (t < e) {
        int d = dst[t];
        int pos = atomicAdd(&cursor[d], 1);
        csr[pos] = src[t];
    }
}

// ---------------- casts (split hi/lo) ----------------

__global__ void k_castx(const float* __restrict__ x, unsigned short* __restrict__ xhi,
                        unsigned short* __restrict__ xlo, int nelem) {
    int t = blockIdx.x * 256 + threadIdx.x;
    if (t < nelem) {
        unsigned short h, l;
        split_bf(x[t], h, l);
        xhi[t] = h; xlo[t] = l;
    }
}

__global__ void k_castw(const float* __restrict__ W, unsigned short* __restrict__ Whi,
                        unsigned short* __restrict__ Wlo, int K, int N) {
    int t = blockIdx.x * 256 + threadIdx.x;
    if (t < K * N) {
        int k = t / N, n = t - k * N;
        unsigned short h, l;
        split_bf(W[t], h, l);
        Whi[n * K + k] = h; Wlo[n * K + k] = l;
    }
}

// ------- split-bf16 MFMA GEMM (NT): C = A @ Bt^T, ~fp32 accuracy ----------
// Output written as fp16 (feeds gathers in agg; 11-bit mantissa is enough).

#define LDP 40

__global__ __launch_bounds__(256) void k_gemm_split(const unsigned short* __restrict__ Ahi,
                                                    const unsigned short* __restrict__ Alo,
                                                    const unsigned short* __restrict__ Bhi,
                                                    const unsigned short* __restrict__ Blo,
                                                    _Float16* __restrict__ C,
                                                    int M, int Ncol, int K) {
    __shared__ unsigned short Ash[64 * LDP];
    __shared__ unsigned short Asl[64 * LDP];
    __shared__ unsigned short Bsh[64 * LDP];
    __shared__ unsigned short Bsl[64 * LDP];
    int t = threadIdx.x;
    int w = t >> 6, lane = t & 63;
    int lrow = lane & 15, kgrp = (lane >> 4) * 8;
    int row0 = blockIdx.x * 64, col0 = blockIdx.y * 64;
    int trow = t >> 2, tcol = (t & 3) * 8;

    f32x4 acc[4] = {{0.f, 0.f, 0.f, 0.f}, {0.f, 0.f, 0.f, 0.f},
                    {0.f, 0.f, 0.f, 0.f}, {0.f, 0.f, 0.f, 0.f}};

    for (int k0 = 0; k0 < K; k0 += 32) {
        uint4 ah = {0u,0u,0u,0u}, al = {0u,0u,0u,0u};
        uint4 bh = {0u,0u,0u,0u}, bl = {0u,0u,0u,0u};
        int gr = row0 + trow;
        if (gr < M) {
            ah = *(const uint4*)(Ahi + (size_t)gr * K + k0 + tcol);
            al = *(const uint4*)(Alo + (size_t)gr * K + k0 + tcol);
        }
        int gc = col0 + trow;
        if (gc < Ncol) {
            bh = *(const uint4*)(Bhi + (size_t)gc * K + k0 + tcol);
            bl = *(const uint4*)(Blo + (size_t)gc * K + k0 + tcol);
        }
        __syncthreads();
        *(uint4*)&Ash[trow * LDP + tcol] = ah;
        *(uint4*)&Asl[trow * LDP + tcol] = al;
        *(uint4*)&Bsh[trow * LDP + tcol] = bh;
        *(uint4*)&Bsl[trow * LDP + tcol] = bl;
        __syncthreads();
        bf16x8 vbh = *(const bf16x8*)&Bsh[(w * 16 + lrow) * LDP + kgrp];
        bf16x8 vbl = *(const bf16x8*)&Bsl[(w * 16 + lrow) * LDP + kgrp];
        #pragma unroll
        for (int mt = 0; mt < 4; ++mt) {
            bf16x8 vah = *(const bf16x8*)&Ash[(mt * 16 + lrow) * LDP + kgrp];
            bf16x8 val = *(const bf16x8*)&Asl[(mt * 16 + lrow) * LDP + kgrp];
            acc[mt] = __builtin_amdgcn_mfma_f32_16x16x32_bf16(vah, vbh, acc[mt], 0, 0, 0);
            acc[mt] = __builtin_amdgcn_mfma_f32_16x16x32_bf16(val, vbh, acc[mt], 0, 0, 0);
            acc[mt] = __builtin_amdgcn_mfma_f32_16x16x32_bf16(vah, vbl, acc[mt], 0, 0, 0);
        }
    }

    int ocol = col0 + w * 16 + lrow;
    if (ocol < Ncol) {
        int orow = (lane >> 4) * 4;
        #pragma unroll
        for (int mt = 0; mt < 4; ++mt) {
            #pragma unroll
            for (int r = 0; r < 4; ++r) {
                int m = row0 + mt * 16 + orow + r;
                if (m < M) C[(size_t)m * Ncol + ocol] = (_Float16)acc[mt][r];
            }
        }
    }
}

static inline void gemm_split(const unsigned short* Ah, const unsigned short* Al,
                              const unsigned short* Bh, const unsigned short* Bl,
                              _Float16* C, int M, int Ncol, int K, hipStream_t st) {
    dim3 g((M + 63) / 64, (Ncol + 63) / 64);
    k_gemm_split<<<g, 256, 0, st>>>(Ah, Al, Bh, Bl, C, M, Ncol, K);
}

// ---------------- attention scores: el/er [N,H] ----------------

template <int H, int D>
__global__ __launch_bounds__(256) void k_attn(const _Float16* __restrict__ feat,
                                              const float* __restrict__ al,
                                              const float* __restrict__ ar,
                                              float* __restrict__ el,
                                              float* __restrict__ er, int n) {
    int gw = blockIdx.x * 4 + (threadIdx.x >> 6);
    int lane = threadIdx.x & 63;
    int i = gw / H, h = gw % H;
    if (i >= n) return;
    float f = (lane < D) ? (float)feat[i * (H * D) + h * D + lane] : 0.f;
    float wl = (lane < D) ? al[h * D + lane] : 0.f;
    float wr = (lane < D) ? ar[h * D + lane] : 0.f;
    float pl = f * wl, pr = f * wr;
    #pragma unroll
    for (int off = 32; off; off >>= 1) {
        pl += __shfl_xor(pl, off);
        pr += __shfl_xor(pr, off);
    }
    if (lane == 0) {
        el[i * H + h] = pl;
        er[i * H + h] = pr;
    }
}

// ---------------- edge-softmax aggregation (LDS chunk staging) -------------
// Per wave: lanes compute (src, ex) for 64 edges once (exp once per edge),
// stage both in per-wave LDS, then the FMA loop reads 4 pairs per
// ds_read_b128 — 0.5 LDS ops/edge vs 2 shfls/edge, gathers issue in bulk.
// Fast path deg<=64 reuses the max-pass registers (one gather round).

__device__ __forceinline__ float lrelu(float v) { return v > 0.f ? v : 0.2f * v; }

// H=4, D=64: one BLOCK per dst node; 256 thr = 4 waves = 4 heads.
template <int ACT, int SPLITOUT>
__global__ __launch_bounds__(256) void k_agg4(const int* __restrict__ rowptr,
                                              const int* __restrict__ csr,
                                              const float* __restrict__ el,
                                              const float* __restrict__ er,
                                              const _Float16* __restrict__ feat,
                                              unsigned short* __restrict__ ohi,
                                              unsigned short* __restrict__ olo,
                                              float* __restrict__ ofp, int n) {
    __shared__ int   s_src[4][64];
    __shared__ float s_ex[4][64];
    int i = blockIdx.x;
    int t = threadIdx.x;
    int h = t >> 6;
    int lane = t & 63;
    int s0 = rowptr[i], s1 = rowptr[i + 1];
    int deg = s1 - s0;
    float eri = er[i * 4 + h];

    float den = 0.f, acc = 0.f;

    if (deg <= 64) {
        int e = s0 + lane;
        int s = 0;
        float v = -INFINITY;
        if (e < s1) {
            s = csr[e];
            v = lrelu(el[s * 4 + h] + eri);
        }
        float m = v;
        #pragma unroll
        for (int off = 32; off; off >>= 1) m = fmaxf(m, __shfl_xor(m, off));
        float ex = (e < s1) ? __expf(v - m) : 0.f;
        den = ex;
        s_src[h][lane] = s;
        s_ex[h][lane] = ex;
        int j = 0;
        for (; j + 4 <= deg; j += 4) {
            int4   sj = *(const int4*)&s_src[h][j];
            float4 xj = *(const float4*)&s_ex[h][j];
            float f0 = (float)feat[(size_t)sj.x * 256 + t];
            float f1 = (float)feat[(size_t)sj.y * 256 + t];
            float f2 = (float)feat[(size_t)sj.z * 256 + t];
            float f3 = (float)feat[(size_t)sj.w * 256 + t];
            acc = fmaf(xj.x, f0, fmaf(xj.y, f1, fmaf(xj.z, f2, fmaf(xj.w, f3, acc))));
        }
        for (; j < deg; ++j)
            acc = fmaf(s_ex[h][j], (float)feat[(size_t)s_src[h][j] * 256 + t], acc);
    } else {
        float m = -INFINITY;
        for (int e = s0 + lane; e < s1; e += 64)
            m = fmaxf(m, lrelu(el[csr[e] * 4 + h] + eri));
        #pragma unroll
        for (int off = 32; off; off >>= 1) m = fmaxf(m, __shfl_xor(m, off));

        for (int c = s0; c < s1; c += 64) {
            int e = c + lane;
            int s = 0;
            float ex = 0.f;
            if (e < s1) {
                s = csr[e];
                ex = __expf(lrelu(el[s * 4 + h] + eri) - m);
            }
            den += ex;
            s_src[h][lane] = s;
            s_ex[h][lane] = ex;
            int cnt = min(64, s1 - c);
            int j = 0;
            for (; j + 4 <= cnt; j += 4) {
                int4   sj = *(const int4*)&s_src[h][j];
                float4 xj = *(const float4*)&s_ex[h][j];
                float f0 = (float)feat[(size_t)sj.x * 256 + t];
                float f1 = (float)feat[(size_t)sj.y * 256 + t];
                float f2 = (float)feat[(size_t)sj.z * 256 + t];
                float f3 = (float)feat[(size_t)sj.w * 256 + t];
                acc = fmaf(xj.x, f0, fmaf(xj.y, f1, fmaf(xj.z, f2, fmaf(xj.w, f3, acc))));
            }
            for (; j < cnt; ++j)
                acc = fmaf(s_ex[h][j], (float)feat[(size_t)s_src[h][j] * 256 + t], acc);
        }
    }
    #pragma unroll
    for (int off = 32; off; off >>= 1) den += __shfl_xor(den, off);

    float o = (s1 > s0) ? acc / fmaxf(den, 1e-9f) : 0.f;
    if (ACT == 1) o = o > 0.f ? o : (__expf(o) - 1.f);
    if (SPLITOUT) {
        unsigned short hh, ll;
        split_bf(o, hh, ll);
        ohi[(size_t)i * 256 + t] = hh;
        olo[(size_t)i * 256 + t] = ll;
    } else {
        ofp[(size_t)i * 256 + t] = o;
    }
}

// H=1: one WAVE per dst node (4 waves/block), same staging structure.
template <int D, int ACT, int SPLITOUT>
__global__ __launch_bounds__(256) void k_agg1(const int* __restrict__ rowptr,
                                              const int* __restrict__ csr,
                                              const float* __restrict__ el,
                                              const float* __restrict__ er,
                                              const _Float16* __restrict__ feat,
                                              unsigned short* __restrict__ ohi,
                                              unsigned short* __restrict__ olo,
                                              float* __restrict__ ofp, int n) {
    __shared__ int   s_src[4][64];
    __shared__ float s_ex[4][64];
    int w = threadIdx.x >> 6;
    int i = blockIdx.x * 4 + w;
    int lane = threadIdx.x & 63;
    if (i >= n) return;
    int s0 = rowptr[i], s1 = rowptr[i + 1];
    int deg = s1 - s0;
    float eri = er[i];
    bool act = lane < D;

    float den = 0.f, acc = 0.f;

    if (deg <= 64) {
        int e = s0 + lane;
        int s = 0;
        float v = -INFINITY;
        if (e < s1) {
            s = csr[e];
            v = lrelu(el[s] + eri);
        }
        float m = v;
        #pragma unroll
        for (int off = 32; off; off >>= 1) m = fmaxf(m, __shfl_xor(m, off));
        float ex = (e < s1) ? __expf(v - m) : 0.f;
        den = ex;
        s_src[w][lane] = s;
        s_ex[w][lane] = ex;
        int j = 0;
        for (; j + 4 <= deg; j += 4) {
            int4   sj = *(const int4*)&s_src[w][j];
            float4 xj = *(const float4*)&s_ex[w][j];
            float f0 = act ? (float)feat[(size_t)sj.x * D + lane] : 0.f;
            float f1 = act ? (float)feat[(size_t)sj.y * D + lane] : 0.f;
            float f2 = act ? (float)feat[(size_t)sj.z * D + lane] : 0.f;
            float f3 = act ? (float)feat[(size_t)sj.w * D + lane] : 0.f;
            acc = fmaf(xj.x, f0, fmaf(xj.y, f1, fmaf(xj.z, f2, fmaf(xj.w, f3, acc))));
        }
        for (; j < deg; ++j)
            acc = fmaf(s_ex[w][j], act ? (float)feat[(size_t)s_src[w][j] * D + lane] : 0.f, acc);
    } else {
        float m = -INFINITY;
        for (int e = s0 + lane; e < s1; e += 64)
            m = fmaxf(m, lrelu(el[csr[e]] + eri));
        #pragma unroll
        for (int off = 32; off; off >>= 1) m = fmaxf(m, __shfl_xor(m, off));

        for (int c = s0; c < s1; c += 64) {
            int e = c + lane;
            int s = 0;
            float ex = 0.f;
            if (e < s1) {
                s = csr[e];
                ex = __expf(lrelu(el[s] + eri) - m);
            }
            den += ex;
            s_src[w][lane] = s;
            s_ex[w][lane] = ex;
            int cnt = min(64, s1 - c);
            int j = 0;
            for (; j + 4 <= cnt; j += 4) {
                int4   sj = *(const int4*)&s_src[w][j];
                float4 xj = *(const float4*)&s_ex[w][j];
                float f0 = act ? (float)feat[(size_t)sj.x * D + lane] : 0.f;
                float f1 = act ? (float)feat[(size_t)sj.y * D + lane] : 0.f;
                float f2 = act ? (float)feat[(size_t)sj.z * D + lane] : 0.f;
                float f3 = act ? (float)feat[(size_t)sj.w * D + lane] : 0.f;
                acc = fmaf(xj.x, f0, fmaf(xj.y, f1, fmaf(xj.z, f2, fmaf(xj.w, f3, acc))));
            }
            for (; j < cnt; ++j)
                acc = fmaf(s_ex[w][j], act ? (float)feat[(size_t)s_src[w][j] * D + lane] : 0.f, acc);
        }
    }
    #pragma unroll
    for (int off = 32; off; off >>= 1) den += __shfl_xor(den, off);

    float o = (s1 > s0) ? acc / fmaxf(den, 1e-9f) : 0.f;
    if (ACT == 1) o = o > 0.f ? o : (__expf(o) - 1.f);
    if (act) {
        if (SPLITOUT) {
            unsigned short hh, ll;
            split_bf(o, hh, ll);
            ohi[(size_t)i * D + lane] = hh;
            olo[(size_t)i * D + lane] = ll;
        } else {
            ofp[(size_t)i * D + lane] = o;
        }
    }
}

// ---------------- launch ----------------

extern "C" void kernel_launch(void* const* d_in, const int* in_sizes, int n_in,
                              void* d_out, int out_size, void* d_ws, size_t ws_size,
                              hipStream_t stream) {
    const float* x    = (const float*)d_in[0];
    const int*   src  = (const int*)d_in[1];
    const int*   dst  = (const int*)d_in[2];
    const float* W00  = (const float*)d_in[3];
    const float* a00l = (const float*)d_in[4];
    const float* a00r = (const float*)d_in[5];
    const float* W01  = (const float*)d_in[6];
    const float* a01l = (const float*)d_in[7];
    const float* a01r = (const float*)d_in[8];
    const float* W0f  = (const float*)d_in[9];
    const float* a0fl = (const float*)d_in[10];
    const float* a0fr = (const float*)d_in[11];
    const float* W10  = (const float*)d_in[12];
    const float* a10l = (const float*)d_in[13];
    const float* a10r = (const float*)d_in[14];
    const float* W1f  = (const float*)d_in[15];
    const float* a1fl = (const float*)d_in[16];
    const float* a1fr = (const float*)d_in[17];
    const float* W1o  = (const float*)d_in[18];
    const float* a1ol = (const float*)d_in[19];
    const float* a1or = (const float*)d_in[20];
    float* out = (float*)d_out;

    const int n = in_sizes[0] / 256;  // 50000
    const int e = in_sizes[1];        // 800000
    const int C = 40;

    char* p = (char*)d_ws;
    auto alloc = [&](size_t bytes) -> void* {
        void* r = (void*)p;
        p += (bytes + 255) & ~(size_t)255;
        return r;
    };
    int*   deg     = (int*)alloc((size_t)n * 4);
    int*   tmp     = (int*)alloc((size_t)n * 4);
    int*   bsum    = (int*)alloc(64 * 4);
    int*   rowptr  = (int*)alloc((size_t)(n + 1) * 4);
    int*   cursor  = (int*)alloc((size_t)n * 4);
    int*   csr     = (int*)alloc((size_t)e * 4);
    float* el      = (float*)alloc((size_t)n * 4 * 4);
    float* er      = (float*)alloc((size_t)n * 4 * 4);
    _Float16* feat = (_Float16*)alloc((size_t)n * 256 * 2 + 256);
    unsigned short* xhi = (unsigned short*)alloc((size_t)n * 256 * 2);
    unsigned short* xlo = (unsigned short*)alloc((size_t)n * 256 * 2);
    unsigned short* hhi = (unsigned short*)alloc((size_t)n * 256 * 2);
    unsigned short* hlo = (unsigned short*)alloc((size_t)n * 256 * 2);
    unsigned short* W00h = (unsigned short*)alloc(256 * 256 * 2);
    unsigned short* W00l = (unsigned short*)alloc(256 * 256 * 2);
    unsigned short* W01h = (unsigned short*)alloc(256 * 64 * 2);
    unsigned short* W01l = (unsigned short*)alloc(256 * 64 * 2);
    unsigned short* W0fh = (unsigned short*)alloc(64 * 40 * 2);
    unsigned short* W0fl = (unsigned short*)alloc(64 * 40 * 2);
    unsigned short* W10h = (unsigned short*)alloc(256 * 256 * 2);
    unsigned short* W10l = (unsigned short*)alloc(256 * 256 * 2);
    unsigned short* W1fh = (unsigned short*)alloc(256 * 64 * 2);
    unsigned short* W1fl = (unsigned short*)alloc(256 * 64 * 2);
    unsigned short* W1oh = (unsigned short*)alloc(64 * 40 * 2);
    unsigned short* W1ol = (unsigned short*)alloc(64 * 40 * 2);

    // ---- CSR build ----
    hipMemsetAsync(deg, 0, (size_t)n * 4, stream);
    k_hist<<<(e + 255) / 256, 256, 0, stream>>>(dst, deg, e);
    int nb = (n + 1023) / 1024;
    k_scan1<<<nb, 1024, 0, stream>>>(deg, tmp, bsum, n);
    k_scan2<<<1, 1, 0, stream>>>(bsum, nb);
    k_scan3<<<(n + 255) / 256, 256, 0, stream>>>(deg, tmp, bsum, rowptr, cursor, n);
    k_scatter<<<(e + 255) / 256, 256, 0, stream>>>(src, dst, cursor, csr, e);

    // ---- casts ----
    int nel = n * 256;
    k_castx<<<(nel + 255) / 256, 256, 0, stream>>>(x, xhi, xlo, nel);
    k_castw<<<(256 * 256 + 255) / 256, 256, 0, stream>>>(W00, W00h, W00l, 256, 256);
    k_castw<<<(256 * 64 + 255) / 256, 256, 0, stream>>>(W01, W01h, W01l, 256, 64);
    k_castw<<<(64 * 40 + 255) / 256, 256, 0, stream>>>(W0f, W0fh, W0fl, 64, 40);
    k_castw<<<(256 * 256 + 255) / 256, 256, 0, stream>>>(W10, W10h, W10l, 256, 256);
    k_castw<<<(256 * 64 + 255) / 256, 256, 0, stream>>>(W1f, W1fh, W1fl, 256, 64);
    k_castw<<<(64 * 40 + 255) / 256, 256, 0, stream>>>(W1o, W1oh, W1ol, 64, 40);

    int gw4 = (n * 4 + 3) / 4;
    int gw1 = (n + 3) / 4;

    // ---- branch 0 ----
    gemm_split(xhi, xlo, W00h, W00l, feat, n, 256, 256, stream);
    k_attn<4, 64><<<gw4, 256, 0, stream>>>(feat, a00l, a00r, el, er, n);
    k_agg4<1, 1><<<n, 256, 0, stream>>>(rowptr, csr, el, er, feat, hhi, hlo, nullptr, n);

    gemm_split(hhi, hlo, W01h, W01l, feat, n, 64, 256, stream);
    k_attn<1, 64><<<gw1, 256, 0, stream>>>(feat, a01l, a01r, el, er, n);
    k_agg1<64, 1, 1><<<gw1, 256, 0, stream>>>(rowptr, csr, el, er, feat, hhi, hlo, nullptr, n);

    gemm_split(hhi, hlo, W0fh, W0fl, feat, n, C, 64, stream);
    k_attn<1, 40><<<gw1, 256, 0, stream>>>(feat, a0fl, a0fr, el, er, n);
    k_agg1<40, 0, 0><<<gw1, 256, 0, stream>>>(rowptr, csr, el, er, feat, nullptr, nullptr, out, n);

    // ---- branch 1 ----
    gemm_split(xhi, xlo, W10h, W10l, feat, n, 256, 256, stream);
    k_attn<4, 64><<<gw4, 256, 0, stream>>>(feat, a10l, a10r, el, er, n);
    k_agg4<1, 1><<<n, 256, 0, stream>>>(rowptr, csr, el, er, feat, hhi, hlo, nullptr, n);

    gemm_split(hhi, hlo, W1fh, W1fl, feat, n, 64, 256, stream);
    k_attn<1, 64><<<gw1, 256, 0, stream>>>(feat, a1fl, a1fr, el, er, n);
    k_agg1<64, 0, 1><<<gw1, 256, 0, stream>>>(rowptr, csr, el, er, feat, hhi, hlo, nullptr, n);

    gemm_split(hhi, hlo, W1oh, W1ol, feat, n, C, 64, stream);
    k_attn<1, 40><<<gw1, 256, 0, stream>>>(feat, a1ol, a1or, el, er, n);
    k_agg1<40, 1, 0><<<gw1, 256, 0, stream>>>(rowptr, csr, el, er, feat, nullptr, nullptr,
                                              out + (size_t)n * C, n);
}

// Round 9
// 769.964 us; speedup vs baseline: 1.2756x; 1.0873x over previous
//
#include <hip/hip_runtime.h>
#include <math.h>

typedef __attribute__((ext_vector_type(8))) short bf16x8;
typedef __attribute__((ext_vector_type(4))) float f32x4;
typedef __attribute__((ext_vector_type(4))) _Float16 f16x4;

__device__ __forceinline__ unsigned short f2bf(float f) {
    unsigned int u = __float_as_uint(f);
    unsigned int r = (u + 0x7FFF + ((u >> 16) & 1)) >> 16;  // RNE
    return (unsigned short)r;
}
__device__ __forceinline__ float bf2f(unsigned short h) {
    return __uint_as_float((unsigned int)h << 16);
}
__device__ __forceinline__ void split_bf(float x, unsigned short& hi, unsigned short& lo) {
    hi = f2bf(x);
    lo = f2bf(x - bf2f(hi));
}

// ---------------- CSR build ----------------

__global__ void k_hist(const int* __restrict__ dst, int* __restrict__ deg, int e) {
    int t = blockIdx.x * 256 + threadIdx.x;
    if (t < e) atomicAdd(&deg[dst[t]], 1);
}

__global__ void k_scan1(const int* __restrict__ deg, int* __restrict__ tmp,
                        int* __restrict__ bsum, int n) {
    __shared__ int s[1024];
    int t = threadIdx.x;
    int g = blockIdx.x * 1024 + t;
    int v = (g < n) ? deg[g] : 0;
    s[t] = v;
    __syncthreads();
    for (int off = 1; off < 1024; off <<= 1) {
        int u = (t >= off) ? s[t - off] : 0;
        __syncthreads();
        s[t] += u;
        __syncthreads();
    }
    if (g < n) tmp[g] = s[t];
    if (t == 1023) bsum[blockIdx.x] = s[t];
}

__global__ void k_scan2(int* bsum, int nb) {
    int acc = 0;
    for (int b = 0; b < nb; ++b) { int v = bsum[b]; bsum[b] = acc; acc += v; }
}

__global__ void k_scan3(const int* __restrict__ deg, const int* __restrict__ tmp,
                        const int* __restrict__ bsum, int* __restrict__ rowptr,
                        int* __restrict__ cursor, int n) {
    int g = blockIdx.x * 256 + threadIdx.x;
    if (g < n) {
        int incl = tmp[g] + bsum[g >> 10];
        rowptr[g + 1] = incl;
        cursor[g] = incl - deg[g];
        if (g == 0) rowptr[0] = 0;
    }
}

__global__ void k_scatter(const int* __restrict__ src, const int* __restrict__ dst,
                          int* __restrict__ cursor, int* __restrict__ csr, int e) {
    int t = blockIdx.x * 256 + threadIdx.x;
    if (t < e) {
        int d = dst[t];
        int pos = atomicAdd(&cursor[d], 1);
        csr[pos] = src[t];
    }
}

// ---------------- casts (split hi/lo) ----------------

__global__ void k_castx(const float* __restrict__ x, unsigned short* __restrict__ xhi,
                        unsigned short* __restrict__ xlo, int nelem) {
    int t = blockIdx.x * 256 + threadIdx.x;
    if (t < nelem) {
        unsigned short h, l;
        split_bf(x[t], h, l);
        xhi[t] = h; xlo[t] = l;
    }
}

__global__ void k_castw(const float* __restrict__ W, unsigned short* __restrict__ Whi,
                        unsigned short* __restrict__ Wlo, int K, int N) {
    int t = blockIdx.x * 256 + threadIdx.x;
    if (t < K * N) {
        int k = t / N, n = t - k * N;
        unsigned short h, l;
        split_bf(W[t], h, l);
        Whi[n * K + k] = h; Wlo[n * K + k] = l;
    }
}

// ------- split-bf16 MFMA GEMM (NT): C = A @ Bt^T, ~fp32 accuracy ----------
// Output written as fp16 (feeds gathers in agg; 11-bit mantissa is enough).

#define LDP 40

__global__ __launch_bounds__(256) void k_gemm_split(const unsigned short* __restrict__ Ahi,
                                                    const unsigned short* __restrict__ Alo,
                                                    const unsigned short* __restrict__ Bhi,
                                                    const unsigned short* __restrict__ Blo,
                                                    _Float16* __restrict__ C,
                                                    int M, int Ncol, int K) {
    __shared__ unsigned short Ash[64 * LDP];
    __shared__ unsigned short Asl[64 * LDP];
    __shared__ unsigned short Bsh[64 * LDP];
    __shared__ unsigned short Bsl[64 * LDP];
    int t = threadIdx.x;
    int w = t >> 6, lane = t & 63;
    int lrow = lane & 15, kgrp = (lane >> 4) * 8;
    int row0 = blockIdx.x * 64, col0 = blockIdx.y * 64;
    int trow = t >> 2, tcol = (t & 3) * 8;

    f32x4 acc[4] = {{0.f, 0.f, 0.f, 0.f}, {0.f, 0.f, 0.f, 0.f},
                    {0.f, 0.f, 0.f, 0.f}, {0.f, 0.f, 0.f, 0.f}};

    for (int k0 = 0; k0 < K; k0 += 32) {
        uint4 ah = {0u,0u,0u,0u}, al = {0u,0u,0u,0u};
        uint4 bh = {0u,0u,0u,0u}, bl = {0u,0u,0u,0u};
        int gr = row0 + trow;
        if (gr < M) {
            ah = *(const uint4*)(Ahi + (size_t)gr * K + k0 + tcol);
            al = *(const uint4*)(Alo + (size_t)gr * K + k0 + tcol);
        }
        int gc = col0 + trow;
        if (gc < Ncol) {
            bh = *(const uint4*)(Bhi + (size_t)gc * K + k0 + tcol);
            bl = *(const uint4*)(Blo + (size_t)gc * K + k0 + tcol);
        }
        __syncthreads();
        *(uint4*)&Ash[trow * LDP + tcol] = ah;
        *(uint4*)&Asl[trow * LDP + tcol] = al;
        *(uint4*)&Bsh[trow * LDP + tcol] = bh;
        *(uint4*)&Bsl[trow * LDP + tcol] = bl;
        __syncthreads();
        bf16x8 vbh = *(const bf16x8*)&Bsh[(w * 16 + lrow) * LDP + kgrp];
        bf16x8 vbl = *(const bf16x8*)&Bsl[(w * 16 + lrow) * LDP + kgrp];
        #pragma unroll
        for (int mt = 0; mt < 4; ++mt) {
            bf16x8 vah = *(const bf16x8*)&Ash[(mt * 16 + lrow) * LDP + kgrp];
            bf16x8 val = *(const bf16x8*)&Asl[(mt * 16 + lrow) * LDP + kgrp];
            acc[mt] = __builtin_amdgcn_mfma_f32_16x16x32_bf16(vah, vbh, acc[mt], 0, 0, 0);
            acc[mt] = __builtin_amdgcn_mfma_f32_16x16x32_bf16(val, vbh, acc[mt], 0, 0, 0);
            acc[mt] = __builtin_amdgcn_mfma_f32_16x16x32_bf16(vah, vbl, acc[mt], 0, 0, 0);
        }
    }

    int ocol = col0 + w * 16 + lrow;
    if (ocol < Ncol) {
        int orow = (lane >> 4) * 4;
        #pragma unroll
        for (int mt = 0; mt < 4; ++mt) {
            #pragma unroll
            for (int r = 0; r < 4; ++r) {
                int m = row0 + mt * 16 + orow + r;
                if (m < M) C[(size_t)m * Ncol + ocol] = (_Float16)acc[mt][r];
            }
        }
    }
}

static inline void gemm_split(const unsigned short* Ah, const unsigned short* Al,
                              const unsigned short* Bh, const unsigned short* Bl,
                              _Float16* C, int M, int Ncol, int K, hipStream_t st) {
    dim3 g((M + 63) / 64, (Ncol + 63) / 64);
    k_gemm_split<<<g, 256, 0, st>>>(Ah, Al, Bh, Bl, C, M, Ncol, K);
}

// ---------------- attention scores: el/er [N,H] ----------------

template <int H, int D>
__global__ __launch_bounds__(256) void k_attn(const _Float16* __restrict__ feat,
                                              const float* __restrict__ al,
                                              const float* __restrict__ ar,
                                              float* __restrict__ el,
                                              float* __restrict__ er, int n) {
    int gw = blockIdx.x * 4 + (threadIdx.x >> 6);
    int lane = threadIdx.x & 63;
    int i = gw / H, h = gw % H;
    if (i >= n) return;
    float f = (lane < D) ? (float)feat[i * (H * D) + h * D + lane] : 0.f;
    float wl = (lane < D) ? al[h * D + lane] : 0.f;
    float wr = (lane < D) ? ar[h * D + lane] : 0.f;
    float pl = f * wl, pr = f * wr;
    #pragma unroll
    for (int off = 32; off; off >>= 1) {
        pl += __shfl_xor(pl, off);
        pr += __shfl_xor(pr, off);
    }
    if (lane == 0) {
        el[i * H + h] = pl;
        er[i * H + h] = pr;
    }
}

__device__ __forceinline__ float lrelu(float v) { return v > 0.f ? v : 0.2f * v; }

// ---------------- H=4 aggregation: ONE WAVE per dst node ------------------
// Lane owns 4 contiguous channels -> one ushort4 (8B) load covers the whole
// 256-ch src row in a single 512B wave transaction per edge. exp stage is
// (edge,head)-parallel: lane=(eidx,h) over 16-edge tiles; per-head butterfly
// over lane-offsets {4,8,16,32}. (src,ex) staged in per-wave LDS.
template <int ACT, int SPLITOUT>
__global__ __launch_bounds__(256) void k_agg4(const int* __restrict__ rowptr,
                                              const int* __restrict__ csr,
                                              const float* __restrict__ el,
                                              const float* __restrict__ er,
                                              const _Float16* __restrict__ feat,
                                              unsigned short* __restrict__ ohi,
                                              unsigned short* __restrict__ olo,
                                              float* __restrict__ ofp, int n) {
    __shared__ int   s_src[4][16];
    __shared__ float s_ex[4][64];
    __shared__ float s_den[4][4];
    int w = threadIdx.x >> 6;
    int lane = threadIdx.x & 63;
    int i = blockIdx.x * 4 + w;
    if (i >= n) return;
    int s0 = rowptr[i], s1 = rowptr[i + 1];
    int deg = s1 - s0;
    int eidx = lane >> 2, h = lane & 3;  // exp-stage role
    int hh = lane >> 4;                  // FMA/output-stage head
    float erh = er[i * 4 + h];

    float den = 0.f;
    float a0 = 0.f, a1 = 0.f, a2 = 0.f, a3 = 0.f;

    auto fma_chunk = [&](int cnt) {
        int j = 0;
        for (; j + 2 <= cnt; j += 2) {
            int sj0 = s_src[w][j], sj1 = s_src[w][j + 1];
            float x0 = s_ex[w][j * 4 + hh], x1 = s_ex[w][(j + 1) * 4 + hh];
            f16x4 f0 = *(const f16x4*)&feat[(size_t)sj0 * 256 + (lane << 2)];
            f16x4 f1 = *(const f16x4*)&feat[(size_t)sj1 * 256 + (lane << 2)];
            a0 = fmaf(x0, (float)f0.x, fmaf(x1, (float)f1.x, a0));
            a1 = fmaf(x0, (float)f0.y, fmaf(x1, (float)f1.y, a1));
            a2 = fmaf(x0, (float)f0.z, fmaf(x1, (float)f1.z, a2));
            a3 = fmaf(x0, (float)f0.w, fmaf(x1, (float)f1.w, a3));
        }
        for (; j < cnt; ++j) {
            int sj = s_src[w][j];
            float x = s_ex[w][j * 4 + hh];
            f16x4 f0 = *(const f16x4*)&feat[(size_t)sj * 256 + (lane << 2)];
            a0 = fmaf(x, (float)f0.x, a0);
            a1 = fmaf(x, (float)f0.y, a1);
            a2 = fmaf(x, (float)f0.z, a2);
            a3 = fmaf(x, (float)f0.w, a3);
        }
    };

    if (deg <= 16) {
        int e = s0 + eidx;
        int s = 0;
        float v = -INFINITY;
        if (e < s1) {
            s = csr[e];
            v = lrelu(el[s * 4 + h] + erh);
        }
        float m = v;
        #pragma unroll
        for (int off = 4; off < 64; off <<= 1) m = fmaxf(m, __shfl_xor(m, off));
        float ex = (e < s1) ? __expf(v - m) : 0.f;
        den = ex;
        if (h == 0) s_src[w][eidx] = s;
        s_ex[w][lane] = ex;
        fma_chunk(deg);
    } else {
        float m = -INFINITY;
        for (int e = s0 + eidx; e < s1; e += 16)
            m = fmaxf(m, lrelu(el[csr[e] * 4 + h] + erh));
        #pragma unroll
        for (int off = 4; off < 64; off <<= 1) m = fmaxf(m, __shfl_xor(m, off));

        for (int c = s0; c < s1; c += 16) {
            int e = c + eidx;
            int s = 0;
            float ex = 0.f;
            if (e < s1) {
                s = csr[e];
                ex = __expf(lrelu(el[s * 4 + h] + erh) - m);
            }
            den += ex;
            if (h == 0) s_src[w][eidx] = s;
            s_ex[w][lane] = ex;
            fma_chunk(min(16, s1 - c));
        }
    }
    #pragma unroll
    for (int off = 4; off < 64; off <<= 1) den += __shfl_xor(den, off);
    if (eidx == 0) s_den[w][h] = den;
    float d = fmaxf(s_den[w][hh], 1e-9f);

    float o0 = (deg > 0) ? a0 / d : 0.f;
    float o1 = (deg > 0) ? a1 / d : 0.f;
    float o2 = (deg > 0) ? a2 / d : 0.f;
    float o3 = (deg > 0) ? a3 / d : 0.f;
    if (ACT == 1) {
        o0 = o0 > 0.f ? o0 : (__expf(o0) - 1.f);
        o1 = o1 > 0.f ? o1 : (__expf(o1) - 1.f);
        o2 = o2 > 0.f ? o2 : (__expf(o2) - 1.f);
        o3 = o3 > 0.f ? o3 : (__expf(o3) - 1.f);
    }
    size_t base = (size_t)i * 256 + (lane << 2);
    if (SPLITOUT) {
        ushort4 vh, vl;
        split_bf(o0, vh.x, vl.x);
        split_bf(o1, vh.y, vl.y);
        split_bf(o2, vh.z, vl.z);
        split_bf(o3, vh.w, vl.w);
        *(ushort4*)&ohi[base] = vh;
        *(ushort4*)&olo[base] = vl;
    } else {
        float4 vo = {o0, o1, o2, o3};
        *(float4*)&ofp[base] = vo;
    }
}

// ---------------- H=1 aggregation (LDS chunk staging, per R8) --------------

template <int D, int ACT, int SPLITOUT>
__global__ __launch_bounds__(256) void k_agg1(const int* __restrict__ rowptr,
                                              const int* __restrict__ csr,
                                              const float* __restrict__ el,
                                              const float* __restrict__ er,
                                              const _Float16* __restrict__ feat,
                                              unsigned short* __restrict__ ohi,
                                              unsigned short* __restrict__ olo,
                                              float* __restrict__ ofp, int n) {
    __shared__ int   s_src[4][64];
    __shared__ float s_ex[4][64];
    int w = threadIdx.x >> 6;
    int i = blockIdx.x * 4 + w;
    int lane = threadIdx.x & 63;
    if (i >= n) return;
    int s0 = rowptr[i], s1 = rowptr[i + 1];
    int deg = s1 - s0;
    float eri = er[i];
    bool act = lane < D;

    float den = 0.f, acc = 0.f;

    if (deg <= 64) {
        int e = s0 + lane;
        int s = 0;
        float v = -INFINITY;
        if (e < s1) {
            s = csr[e];
            v = lrelu(el[s] + eri);
        }
        float m = v;
        #pragma unroll
        for (int off = 32; off; off >>= 1) m = fmaxf(m, __shfl_xor(m, off));
        float ex = (e < s1) ? __expf(v - m) : 0.f;
        den = ex;
        s_src[w][lane] = s;
        s_ex[w][lane] = ex;
        int j = 0;
        for (; j + 4 <= deg; j += 4) {
            int4   sj = *(const int4*)&s_src[w][j];
            float4 xj = *(const float4*)&s_ex[w][j];
            float f0 = act ? (float)feat[(size_t)sj.x * D + lane] : 0.f;
            float f1 = act ? (float)feat[(size_t)sj.y * D + lane] : 0.f;
            float f2 = act ? (float)feat[(size_t)sj.z * D + lane] : 0.f;
            float f3 = act ? (float)feat[(size_t)sj.w * D + lane] : 0.f;
            acc = fmaf(xj.x, f0, fmaf(xj.y, f1, fmaf(xj.z, f2, fmaf(xj.w, f3, acc))));
        }
        for (; j < deg; ++j)
            acc = fmaf(s_ex[w][j], act ? (float)feat[(size_t)s_src[w][j] * D + lane] : 0.f, acc);
    } else {
        float m = -INFINITY;
        for (int e = s0 + lane; e < s1; e += 64)
            m = fmaxf(m, lrelu(el[csr[e]] + eri));
        #pragma unroll
        for (int off = 32; off; off >>= 1) m = fmaxf(m, __shfl_xor(m, off));

        for (int c = s0; c < s1; c += 64) {
            int e = c + lane;
            int s = 0;
            float ex = 0.f;
            if (e < s1) {
                s = csr[e];
                ex = __expf(lrelu(el[s] + eri) - m);
            }
            den += ex;
            s_src[w][lane] = s;
            s_ex[w][lane] = ex;
            int cnt = min(64, s1 - c);
            int j = 0;
            for (; j + 4 <= cnt; j += 4) {
                int4   sj = *(const int4*)&s_src[w][j];
                float4 xj = *(const float4*)&s_ex[w][j];
                float f0 = act ? (float)feat[(size_t)sj.x * D + lane] : 0.f;
                float f1 = act ? (float)feat[(size_t)sj.y * D + lane] : 0.f;
                float f2 = act ? (float)feat[(size_t)sj.z * D + lane] : 0.f;
                float f3 = act ? (float)feat[(size_t)sj.w * D + lane] : 0.f;
                acc = fmaf(xj.x, f0, fmaf(xj.y, f1, fmaf(xj.z, f2, fmaf(xj.w, f3, acc))));
            }
            for (; j < cnt; ++j)
                acc = fmaf(s_ex[w][j], act ? (float)feat[(size_t)s_src[w][j] * D + lane] : 0.f, acc);
        }
    }
    #pragma unroll
    for (int off = 32; off; off >>= 1) den += __shfl_xor(den, off);

    float o = (s1 > s0) ? acc / fmaxf(den, 1e-9f) : 0.f;
    if (ACT == 1) o = o > 0.f ? o : (__expf(o) - 1.f);
    if (act) {
        if (SPLITOUT) {
            unsigned short hh, ll;
            split_bf(o, hh, ll);
            ohi[(size_t)i * D + lane] = hh;
            olo[(size_t)i * D + lane] = ll;
        } else {
            ofp[(size_t)i * D + lane] = o;
        }
    }
}

// ---------------- launch ----------------

extern "C" void kernel_launch(void* const* d_in, const int* in_sizes, int n_in,
                              void* d_out, int out_size, void* d_ws, size_t ws_size,
                              hipStream_t stream) {
    const float* x    = (const float*)d_in[0];
    const int*   src  = (const int*)d_in[1];
    const int*   dst  = (const int*)d_in[2];
    const float* W00  = (const float*)d_in[3];
    const float* a00l = (const float*)d_in[4];
    const float* a00r = (const float*)d_in[5];
    const float* W01  = (const float*)d_in[6];
    const float* a01l = (const float*)d_in[7];
    const float* a01r = (const float*)d_in[8];
    const float* W0f  = (const float*)d_in[9];
    const float* a0fl = (const float*)d_in[10];
    const float* a0fr = (const float*)d_in[11];
    const float* W10  = (const float*)d_in[12];
    const float* a10l = (const float*)d_in[13];
    const float* a10r = (const float*)d_in[14];
    const float* W1f  = (const float*)d_in[15];
    const float* a1fl = (const float*)d_in[16];
    const float* a1fr = (const float*)d_in[17];
    const float* W1o  = (const float*)d_in[18];
    const float* a1ol = (const float*)d_in[19];
    const float* a1or = (const float*)d_in[20];
    float* out = (float*)d_out;

    const int n = in_sizes[0] / 256;  // 50000
    const int e = in_sizes[1];        // 800000
    const int C = 40;

    char* p = (char*)d_ws;
    auto alloc = [&](size_t bytes) -> void* {
        void* r = (void*)p;
        p += (bytes + 255) & ~(size_t)255;
        return r;
    };
    int*   deg     = (int*)alloc((size_t)n * 4);
    int*   tmp     = (int*)alloc((size_t)n * 4);
    int*   bsum    = (int*)alloc(64 * 4);
    int*   rowptr  = (int*)alloc((size_t)(n + 1) * 4);
    int*   cursor  = (int*)alloc((size_t)n * 4);
    int*   csr     = (int*)alloc((size_t)e * 4);
    float* el      = (float*)alloc((size_t)n * 4 * 4);
    float* er      = (float*)alloc((size_t)n * 4 * 4);
    _Float16* feat = (_Float16*)alloc((size_t)n * 256 * 2 + 256);
    unsigned short* xhi = (unsigned short*)alloc((size_t)n * 256 * 2);
    unsigned short* xlo = (unsigned short*)alloc((size_t)n * 256 * 2);
    unsigned short* hhi = (unsigned short*)alloc((size_t)n * 256 * 2);
    unsigned short* hlo = (unsigned short*)alloc((size_t)n * 256 * 2);
    unsigned short* W00h = (unsigned short*)alloc(256 * 256 * 2);
    unsigned short* W00l = (unsigned short*)alloc(256 * 256 * 2);
    unsigned short* W01h = (unsigned short*)alloc(256 * 64 * 2);
    unsigned short* W01l = (unsigned short*)alloc(256 * 64 * 2);
    unsigned short* W0fh = (unsigned short*)alloc(64 * 40 * 2);
    unsigned short* W0fl = (unsigned short*)alloc(64 * 40 * 2);
    unsigned short* W10h = (unsigned short*)alloc(256 * 256 * 2);
    unsigned short* W10l = (unsigned short*)alloc(256 * 256 * 2);
    unsigned short* W1fh = (unsigned short*)alloc(256 * 64 * 2);
    unsigned short* W1fl = (unsigned short*)alloc(256 * 64 * 2);
    unsigned short* W1oh = (unsigned short*)alloc(64 * 40 * 2);
    unsigned short* W1ol = (unsigned short*)alloc(64 * 40 * 2);

    // ---- CSR build ----
    hipMemsetAsync(deg, 0, (size_t)n * 4, stream);
    k_hist<<<(e + 255) / 256, 256, 0, stream>>>(dst, deg, e);
    int nb = (n + 1023) / 1024;
    k_scan1<<<nb, 1024, 0, stream>>>(deg, tmp, bsum, n);
    k_scan2<<<1, 1, 0, stream>>>(bsum, nb);
    k_scan3<<<(n + 255) / 256, 256, 0, stream>>>(deg, tmp, bsum, rowptr, cursor, n);
    k_scatter<<<(e + 255) / 256, 256, 0, stream>>>(src, dst, cursor, csr, e);

    // ---- casts ----
    int nel = n * 256;
    k_castx<<<(nel + 255) / 256, 256, 0, stream>>>(x, xhi, xlo, nel);
    k_castw<<<(256 * 256 + 255) / 256, 256, 0, stream>>>(W00, W00h, W00l, 256, 256);
    k_castw<<<(256 * 64 + 255) / 256, 256, 0, stream>>>(W01, W01h, W01l, 256, 64);
    k_castw<<<(64 * 40 + 255) / 256, 256, 0, stream>>>(W0f, W0fh, W0fl, 64, 40);
    k_castw<<<(256 * 256 + 255) / 256, 256, 0, stream>>>(W10, W10h, W10l, 256, 256);
    k_castw<<<(256 * 64 + 255) / 256, 256, 0, stream>>>(W1f, W1fh, W1fl, 256, 64);
    k_castw<<<(64 * 40 + 255) / 256, 256, 0, stream>>>(W1o, W1oh, W1ol, 64, 40);

    int gw4 = (n * 4 + 3) / 4;
    int gw1 = (n + 3) / 4;

    // ---- branch 0 ----
    gemm_split(xhi, xlo, W00h, W00l, feat, n, 256, 256, stream);
    k_attn<4, 64><<<gw4, 256, 0, stream>>>(feat, a00l, a00r, el, er, n);
    k_agg4<1, 1><<<gw1, 256, 0, stream>>>(rowptr, csr, el, er, feat, hhi, hlo, nullptr, n);

    gemm_split(hhi, hlo, W01h, W01l, feat, n, 64, 256, stream);
    k_attn<1, 64><<<gw1, 256, 0, stream>>>(feat, a01l, a01r, el, er, n);
    k_agg1<64, 1, 1><<<gw1, 256, 0, stream>>>(rowptr, csr, el, er, feat, hhi, hlo, nullptr, n);

    gemm_split(hhi, hlo, W0fh, W0fl, feat, n, C, 64, stream);
    k_attn<1, 40><<<gw1, 256, 0, stream>>>(feat, a0fl, a0fr, el, er, n);
    k_agg1<40, 0, 0><<<gw1, 256, 0, stream>>>(rowptr, csr, el, er, feat, nullptr, nullptr, out, n);

    // ---- branch 1 ----
    gemm_split(xhi, xlo, W10h, W10l, feat, n, 256, 256, stream);
    k_attn<4, 64><<<gw4, 256, 0, stream>>>(feat, a10l, a10r, el, er, n);
    k_agg4<1, 1><<<gw1, 256, 0, stream>>>(rowptr, csr, el, er, feat, hhi, hlo, nullptr, n);

    gemm_split(hhi, hlo, W1fh, W1fl, feat, n, 64, 256, stream);
    k_attn<1, 64><<<gw1, 256, 0, stream>>>(feat, a1fl, a1fr, el, er, n);
    k_agg1<64, 0, 1><<<gw1, 256, 0, stream>>>(rowptr, csr, el, er, feat, hhi, hlo, nullptr, n);

    gemm_split(hhi, hlo, W1oh, W1ol, feat, n, C, 64, stream);
    k_attn<1, 40><<<gw1, 256, 0, stream>>>(feat, a1ol, a1or, el, er, n);
    k_agg1<40, 1, 0><<<gw1, 256, 0, stream>>>(rowptr, csr, el, er, feat, nullptr, nullptr,
                                              out + (size_t)n * C, n);
}